// Round 17
// baseline (116.638 us; speedup 1.0000x reference)
//
#include <hip/hip_runtime.h>
#include <hip/hip_bf16.h>

#define NN 65536
#define KK 2048
#define DD 128

typedef __attribute__((ext_vector_type(8))) _Float16 f16x8;
typedef __attribute__((ext_vector_type(16))) float f32x16;

static __device__ __forceinline__ unsigned encf(float f) {
    unsigned u = __float_as_uint(f);
    return u ^ (((unsigned)((int)u >> 31)) | 0x80000000u);   // monotone float->uint
}

static __device__ __forceinline__ void gll16(const void* g, void* l) {
    __builtin_amdgcn_global_load_lds(
        (const __attribute__((address_space(1))) void*)g,
        (__attribute__((address_space(3))) void*)l, 16, 0, 0);
}

// ---- prep (W only): Wre frag-order (x128) + w2 ----
// Wre: [colblk128][ct:4][t:8][g:2][col32][8] halfs
// (64-col tile i is the contiguous 8192-half span Wre + i*8192)
__global__ __launch_bounds__(256) void vq_prep(const float* __restrict__ Wd,
                                               _Float16* __restrict__ Wre,
                                               float* __restrict__ w2)
{
    int tid = threadIdx.x;
    int rl = tid >> 4, c = tid & 15;          // 16 rows x 16 chunks of 8
    int r = blockIdx.x * 16 + rl;             // 0..2047
    const float4* wp = reinterpret_cast<const float4*>(Wd + (size_t)r * DD + c * 8);
    float4 v0 = wp[0], v1 = wp[1];
    float v[8] = {v0.x, v0.y, v0.z, v0.w, v1.x, v1.y, v1.z, v1.w};

    f16x8 hv;
#pragma unroll
    for (int j = 0; j < 8; ++j) hv[j] = (_Float16)(v[j] * 128.0f);

    float p = 0.f;
#pragma unroll
    for (int j = 0; j < 8; ++j) p = fmaf(v[j], v[j], p);
#pragma unroll
    for (int off2 = 1; off2 < 16; off2 <<= 1) p += __shfl_xor(p, off2, 64);

    int t = c >> 1, g = c & 1;
    size_t off = (size_t)(r >> 7) * 16384 + (size_t)((r >> 5) & 3) * 4096
               + t * 512 + g * 256 + (size_t)(r & 31) * 8;
    *reinterpret_cast<f16x8*>(Wre + off) = hv;
    if (c == 0) w2[r] = p;
}

// ---- MFMA distance GEMM (64-col steps, 3 blocks/CU) + fused resolve ----
// 128 rows x 2048 cols per block, 4 waves x 32 rows, 32x32x16 MFMA.
// A-frags converted directly from Z. 32 steps of 64 cols; B double-buffered
// (2 x 16KB) in LDS via counted-vmcnt gll16 prefetch. LDS total ~41KB ->
// 3 blocks/CU = 3 waves/SIMD (champion had 2).
__global__ __launch_bounds__(256, 3) void vq_gemm(const float* __restrict__ Z,
                                                  const _Float16* __restrict__ Wre,
                                                  const float* __restrict__ w2g,
                                                  const float* __restrict__ Wd,
                                                  int* __restrict__ assign,
                                                  float* __restrict__ counts)
{
    int rb  = blockIdx.x;                     // 0..511
    int tid = threadIdx.x;
    int wid = tid >> 6, lane = tid & 63;
    int g2 = lane >> 5, l31 = lane & 31;

    __shared__ _Float16 Bs[2][8192];          // 2 x 16KB
    __shared__ float W2s[2048];               // 8KB
    __shared__ float2 T2s[128];               // 1KB

    // prologue: stage w2 (2 loads) + tile-0 B (4 loads)
#pragma unroll
    for (int j = 0; j < 2; ++j)
        gll16(w2g + j * 1024 + tid * 4, &W2s[j * 1024 + tid * 4]);
#pragma unroll
    for (int j = 0; j < 4; ++j)
        gll16(Wre + j * 2048 + tid * 8, &Bs[0][j * 2048 + tid * 8]);

    // A fragments straight from Z: row = rb*128 + wid*32 + l31
    const float* zrow = Z + ((size_t)(rb * 128 + wid * 32 + l31)) * DD + g2 * 8;
    f16x8 a[8];
#pragma unroll
    for (int t = 0; t < 8; ++t) {
        float4 u0 = *reinterpret_cast<const float4*>(zrow + t * 16);
        float4 u1 = *reinterpret_cast<const float4*>(zrow + t * 16 + 4);
        f16x8 h;
        h[0] = (_Float16)u0.x; h[1] = (_Float16)u0.y;
        h[2] = (_Float16)u0.z; h[3] = (_Float16)u0.w;
        h[4] = (_Float16)u1.x; h[5] = (_Float16)u1.y;
        h[6] = (_Float16)u1.z; h[7] = (_Float16)u1.w;
        a[t] = h;
    }

    const float INF = __uint_as_float(0x7F800000u);
    float t1[16], t2[16];
#pragma unroll
    for (int s = 0; s < 16; ++s) { t1[s] = INF; t2[s] = INF; }

    const f32x16 zz = {};

    int cur = 0;
#pragma unroll 1
    for (int it = 0; it < 32; ++it) {
        if (it < 31) {
            const _Float16* wb = Wre + (size_t)(it + 1) * 8192;
#pragma unroll
            for (int j = 0; j < 4; ++j)
                gll16(wb + j * 2048 + tid * 8, &Bs[cur ^ 1][j * 2048 + tid * 8]);
            asm volatile("s_waitcnt vmcnt(4)" ::: "memory");  // cur landed, next in flight
        } else {
            asm volatile("s_waitcnt vmcnt(0)" ::: "memory");
        }
        __builtin_amdgcn_s_barrier();

        float w2v[2];
        w2v[0] = W2s[it * 64 + l31];
        w2v[1] = W2s[it * 64 + 32 + l31];

        const _Float16* bb = &Bs[cur][g2 * 256 + l31 * 8];
        f32x16 acc[2];
        __builtin_amdgcn_s_setprio(1);
#pragma unroll
        for (int ct = 0; ct < 2; ++ct) {
#pragma unroll
            for (int t = 0; t < 8; ++t) {
                f16x8 b = *reinterpret_cast<const f16x8*>(bb + ct * 4096 + t * 512);
                acc[ct] = __builtin_amdgcn_mfma_f32_32x32x16_f16(
                    a[t], b, (t == 0) ? zz : acc[ct], 0, 0, 0);
            }
        }
        __builtin_amdgcn_s_setprio(0);

        // epilogue: d = w2 - acc/64 ; per-row top-2 MIN, col idx in low 11 bits
#pragma unroll
        for (int ct = 0; ct < 2; ++ct) {
            unsigned ci = (unsigned)(it * 64 + ct * 32 + l31);
#pragma unroll
            for (int r = 0; r < 16; ++r) {
                float d = fmaf(-0.015625f, acc[ct][r], w2v[ct]);
                float df = __uint_as_float((__float_as_uint(d) & 0xFFFFF800u) | ci);
                t2[r] = __builtin_amdgcn_fmed3f(df, t1[r], t2[r]);
                t1[r] = fminf(t1[r], df);
            }
        }

        __builtin_amdgcn_s_barrier();
        cur ^= 1;
    }

    // merge across the 32 col-lanes (min semantics); rows differ by g2
#pragma unroll
    for (int s = 0; s < 16; ++s) {
        float v1 = t1[s], v2 = t2[s];
#pragma unroll
        for (int msk = 1; msk < 32; msk <<= 1) {
            float o1 = __shfl_xor(v1, msk, 64);
            float o2 = __shfl_xor(v2, msk, 64);
            float mx = fmaxf(v1, o1);
            v1 = fminf(v1, o1);
            v2 = fminf(fminf(v2, o2), mx);
        }
        if (l31 == 0) {
            int rl = wid * 32 + (s & 3) + 8 * (s >> 2) + 4 * g2;
            T2s[rl] = make_float2(v1, v2);
        }
    }
    __syncthreads();

    // fused resolve: delta-guarded exact fp32 re-score (rare), assign+count
    if (tid < 128) {
        int row = rb * 128 + tid;
        float2 t2v = T2s[tid];
        unsigned u1 = __float_as_uint(t2v.x);
        unsigned u2 = __float_as_uint(t2v.y);
        int c1 = (int)(u1 & 2047u), c2 = (int)(u2 & 2047u);
        float d1 = __uint_as_float(u1 & 0xFFFFF800u);
        float d2 = __uint_as_float(u2 & 0xFFFFF800u);

        int res = c1;
        if (d2 - d1 <= 1e-3f) {
            int cols[2] = {c1, c2};
            const float4* zp = reinterpret_cast<const float4*>(Z + (size_t)row * DD);
            float s0 = 0.f, s1 = 0.f, s2 = 0.f, s3 = 0.f;
            for (int q = 0; q < 32; ++q) {
                float4 z = zp[q];
                s0 = fmaf(z.x, z.x, s0);
                s1 = fmaf(z.y, z.y, s1);
                s2 = fmaf(z.z, z.z, s2);
                s3 = fmaf(z.w, z.w, s3);
            }
            float z2v = (s0 + s1) + (s2 + s3);
            unsigned long long be = ~0ull;
            for (int i = 0; i < 2; ++i) {
                int k = cols[i];
                const float4* wp = reinterpret_cast<const float4*>(Wd + (size_t)k * DD);
                float a0 = 0.f, a1 = 0.f, a2 = 0.f, a3 = 0.f;
                for (int q = 0; q < 32; ++q) {
                    float4 zq = zp[q];
                    float4 wq = wp[q];
                    a0 = fmaf(zq.x, wq.x, a0);
                    a1 = fmaf(zq.y, wq.y, a1);
                    a2 = fmaf(zq.z, wq.z, a2);
                    a3 = fmaf(zq.w, wq.w, a3);
                }
                float sdot = (a0 + a1) + (a2 + a3);
                float tt = __fsub_rn(z2v, __fmul_rn(2.0f, sdot));
                float dist = __fadd_rn(tt, W2s[k]);
                unsigned long long key =
                    (((unsigned long long)encf(dist)) << 32) | (unsigned)k;
                if (key < be) be = key;
            }
            res = (int)(be & 0xffffffffu);
        }
        assign[row] = res;
        atomicAdd(&counts[res], 1.0f);
    }
}

// ---- scan: exclusive prefix over 2048 counts -> start, cursor ----
__global__ __launch_bounds__(256) void vq_scan(const float* __restrict__ counts,
                                               int* __restrict__ start,
                                               int* __restrict__ cursor)
{
    __shared__ int ps[256];
    int tid = threadIdx.x;
    int c[8];
    int tot = 0;
#pragma unroll
    for (int j = 0; j < 8; ++j) { c[j] = (int)counts[tid * 8 + j]; tot += c[j]; }
    ps[tid] = tot;
    __syncthreads();
    for (int off = 1; off < 256; off <<= 1) {
        int v = (tid >= off) ? ps[tid - off] : 0;
        __syncthreads();
        ps[tid] += v;
        __syncthreads();
    }
    int base = ps[tid] - tot;
#pragma unroll
    for (int j = 0; j < 8; ++j) {
        start[tid * 8 + j] = base;
        cursor[tid * 8 + j] = base;
        base += c[j];
    }
}

// ---- permute: row ids grouped by assigned code ----
__global__ __launch_bounds__(256) void vq_permute(const int* __restrict__ assign,
                                                  int* __restrict__ cursor,
                                                  int* __restrict__ order)
{
    int row = blockIdx.x * 256 + threadIdx.x;
    int k = assign[row];
    int pos = atomicAdd(&cursor[k], 1);
    order[pos] = row;
}

// ---- accumulate + update + st_out scatter + exact commit-loss ----
__global__ __launch_bounds__(128) void vq_accum_update(const float* __restrict__ Z,
                                                       const float* __restrict__ Wd,
                                                       const float* __restrict__ dict_cnt,
                                                       const float* __restrict__ counts,
                                                       const int* __restrict__ start,
                                                       const int* __restrict__ order,
                                                       float* __restrict__ w_new_out,
                                                       float* __restrict__ c_new_out,
                                                       float* __restrict__ st_out,
                                                       float* __restrict__ bins)
{
    int k = blockIdx.x;
    int d = threadIdx.x;
    int n = (int)counts[k];
    int st = start[k];

    float sum = 0.f, sq = 0.f;
    int i = 0;
    for (; i + 8 <= n; i += 8) {
        int o0 = order[st + i + 0];
        int o1 = order[st + i + 1];
        int o2 = order[st + i + 2];
        int o3 = order[st + i + 3];
        int o4 = order[st + i + 4];
        int o5 = order[st + i + 5];
        int o6 = order[st + i + 6];
        int o7 = order[st + i + 7];
        float v0 = Z[(size_t)o0 * DD + d];
        float v1 = Z[(size_t)o1 * DD + d];
        float v2 = Z[(size_t)o2 * DD + d];
        float v3 = Z[(size_t)o3 * DD + d];
        float v4 = Z[(size_t)o4 * DD + d];
        float v5 = Z[(size_t)o5 * DD + d];
        float v6 = Z[(size_t)o6 * DD + d];
        float v7 = Z[(size_t)o7 * DD + d];
        sum += ((v0 + v1) + (v2 + v3)) + ((v4 + v5) + (v6 + v7));
        sq = fmaf(v0, v0, sq);
        sq = fmaf(v1, v1, sq);
        sq = fmaf(v2, v2, sq);
        sq = fmaf(v3, v3, sq);
        sq = fmaf(v4, v4, sq);
        sq = fmaf(v5, v5, sq);
        sq = fmaf(v6, v6, sq);
        sq = fmaf(v7, v7, sq);
    }
    for (; i < n; ++i) {
        float v = Z[(size_t)order[st + i] * DD + d];
        sum += v;
        sq = fmaf(v, v, sq);
    }

    float cnt = dict_cnt[k];
    float ck = counts[k];
    bool assigned = n > 0;
    float cn = assigned ? __fadd_rn(__fmul_rn(0.99f, cnt), __fmul_rn(0.01f, ck)) : cnt;
    float w = Wd[(size_t)k * DD + d];
    float wn = w;
    if (assigned) {
        float num = __fmul_rn(0.01f, sum);
        wn = __fadd_rn(__fmul_rn(0.99f, w), num / fmaxf(cn, 1e-12f));
    }
    w_new_out[(size_t)k * DD + d] = wn;
    if (d == 0) c_new_out[k] = cn;

    // straight-through output: every row of this cluster gets w_new[k]
    int j = 0;
    for (; j + 8 <= n; j += 8) {
        int o0 = order[st + j + 0];
        int o1 = order[st + j + 1];
        int o2 = order[st + j + 2];
        int o3 = order[st + j + 3];
        int o4 = order[st + j + 4];
        int o5 = order[st + j + 5];
        int o6 = order[st + j + 6];
        int o7 = order[st + j + 7];
        st_out[(size_t)o0 * DD + d] = wn;
        st_out[(size_t)o1 * DD + d] = wn;
        st_out[(size_t)o2 * DD + d] = wn;
        st_out[(size_t)o3 * DD + d] = wn;
        st_out[(size_t)o4 * DD + d] = wn;
        st_out[(size_t)o5 * DD + d] = wn;
        st_out[(size_t)o6 * DD + d] = wn;
        st_out[(size_t)o7 * DD + d] = wn;
    }
    for (; j < n; ++j)
        st_out[(size_t)order[st + j] * DD + d] = wn;

    // exact commit-loss partial: sum_i (z_i - wn)^2 = sq - 2*wn*sum + n*wn^2
    float p = fmaf(ck, wn * wn, fmaf(-2.0f * wn, sum, sq));
#pragma unroll
    for (int off = 32; off; off >>= 1) p += __shfl_down(p, off, 64);
    __shared__ float sm[2];
    if ((threadIdx.x & 63) == 0) sm[threadIdx.x >> 6] = p;
    __syncthreads();
    if (threadIdx.x == 0) atomicAdd(&bins[(k & 63) * 16], sm[0] + sm[1]);
}

// ---- finish: loss = sum(bins)/N ----
__global__ void vq_finish(const float* __restrict__ bins,
                          float* __restrict__ out_loss)
{
    if (threadIdx.x == 0) {
        float s = 0.f;
        for (int i = 0; i < 64; ++i) s += bins[i * 16];
        out_loss[0] = s * (1.0f / 65536.0f);
    }
}

extern "C" void kernel_launch(void* const* d_in, const int* in_sizes, int n_in,
                              void* d_out, int out_size, void* d_ws, size_t ws_size,
                              hipStream_t stream)
{
    const float* Z        = (const float*)d_in[0];
    const float* Wd       = (const float*)d_in[1];
    const float* dict_cnt = (const float*)d_in[2];

    float* out      = (float*)d_out;
    float* st_out   = out;
    float* out_loss = out + (size_t)NN * DD;
    float* w_new    = out_loss + 1;
    float* c_new    = w_new + (size_t)KK * DD;

    char* ws = (char*)d_ws;
    _Float16* Wre  = (_Float16*)ws;                      //    524,288 B
    float* w2      = (float*)(ws + 524288);              //      8,192 B
    int* assign    = (int*)(ws + 532480);                //    262,144 B
    float* counts  = (float*)(ws + 794624);              //      8,192 B
    float* bins    = (float*)(ws + 802816);              //      4,096 B
    int* start     = (int*)(ws + 806912);                //      8,192 B
    int* cursor    = (int*)(ws + 815104);                //      8,192 B
    int* order     = (int*)(ws + 823296);                //    262,144 B

    // counts + bins contiguous: one memset
    hipMemsetAsync(counts, 0, 8192 + 4096, stream);

    vq_prep<<<KK / 16, 256, 0, stream>>>(Wd, Wre, w2);
    vq_gemm<<<NN / 128, 256, 0, stream>>>(Z, Wre, w2, Wd, assign, counts);
    vq_scan<<<1, 256, 0, stream>>>(counts, start, cursor);
    vq_permute<<<NN / 256, 256, 0, stream>>>(assign, cursor, order);
    vq_accum_update<<<KK, 128, 0, stream>>>(Z, Wd, dict_cnt, counts, start, order,
                                            w_new, c_new, st_out, bins);
    vq_finish<<<1, 64, 0, stream>>>(bins, out_loss);
}

// Round 18
// 105.882 us; speedup vs baseline: 1.1016x; 1.1016x over previous
//
#include <hip/hip_runtime.h>
#include <hip/hip_bf16.h>

#define NN 65536
#define KK 2048
#define DD 128

typedef __attribute__((ext_vector_type(8))) _Float16 f16x8;
typedef __attribute__((ext_vector_type(16))) float f32x16;

static __device__ __forceinline__ unsigned encf(float f) {
    unsigned u = __float_as_uint(f);
    return u ^ (((unsigned)((int)u >> 31)) | 0x80000000u);   // monotone float->uint
}

static __device__ __forceinline__ void gll16(const void* g, void* l) {
    __builtin_amdgcn_global_load_lds(
        (const __attribute__((address_space(1))) void*)g,
        (__attribute__((address_space(3))) void*)l, 16, 0, 0);
}

// ---- prep (W only): Wre frag-order (x128) + w2 ----
// Wre: [colblk128][ct:4][t:8][g:2][col32][8] halfs
__global__ __launch_bounds__(256) void vq_prep(const float* __restrict__ Wd,
                                               _Float16* __restrict__ Wre,
                                               float* __restrict__ w2)
{
    int tid = threadIdx.x;
    int rl = tid >> 4, c = tid & 15;          // 16 rows x 16 chunks of 8
    int r = blockIdx.x * 16 + rl;             // 0..2047
    const float4* wp = reinterpret_cast<const float4*>(Wd + (size_t)r * DD + c * 8);
    float4 v0 = wp[0], v1 = wp[1];
    float v[8] = {v0.x, v0.y, v0.z, v0.w, v1.x, v1.y, v1.z, v1.w};

    f16x8 hv;
#pragma unroll
    for (int j = 0; j < 8; ++j) hv[j] = (_Float16)(v[j] * 128.0f);

    float p = 0.f;
#pragma unroll
    for (int j = 0; j < 8; ++j) p = fmaf(v[j], v[j], p);
#pragma unroll
    for (int off2 = 1; off2 < 16; off2 <<= 1) p += __shfl_xor(p, off2, 64);

    int t = c >> 1, g = c & 1;
    size_t off = (size_t)(r >> 7) * 16384 + (size_t)((r >> 5) & 3) * 4096
               + t * 512 + g * 256 + (size_t)(r & 31) * 8;
    *reinterpret_cast<f16x8*>(Wre + off) = hv;
    if (c == 0) w2[r] = p;
}

// ---- MFMA distance GEMM (champion) + fused resolve ----
// 128 rows x 2048 cols per block, 4 waves x 32 rows, 32x32x16 MFMA.
// A-frags converted directly from Z. 16 steps of 128 cols; B double-buffered
// in LDS via counted-vmcnt gll16 prefetch.
__global__ __launch_bounds__(256, 2) void vq_gemm(const float* __restrict__ Z,
                                                  const _Float16* __restrict__ Wre,
                                                  const float* __restrict__ w2g,
                                                  const float* __restrict__ Wd,
                                                  int* __restrict__ assign,
                                                  float* __restrict__ counts)
{
    int rb  = blockIdx.x;                     // 0..511
    int tid = threadIdx.x;
    int wid = tid >> 6, lane = tid & 63;
    int g2 = lane >> 5, l31 = lane & 31;

    __shared__ _Float16 Bs[2][16384];         // 2 x 32KB
    __shared__ float W2s[2048];               // 8KB
    __shared__ float2 T2s[128];               // 1KB

    // prologue: stage w2 (2 loads) + step-0 B tile (8 loads)
#pragma unroll
    for (int j = 0; j < 2; ++j)
        gll16(w2g + j * 1024 + tid * 4, &W2s[j * 1024 + tid * 4]);
#pragma unroll
    for (int j = 0; j < 8; ++j)
        gll16(Wre + j * 2048 + tid * 8, &Bs[0][j * 2048 + tid * 8]);

    // A fragments straight from Z: row = rb*128 + wid*32 + l31
    const float* zrow = Z + ((size_t)(rb * 128 + wid * 32 + l31)) * DD + g2 * 8;
    f16x8 a[8];
#pragma unroll
    for (int t = 0; t < 8; ++t) {
        float4 u0 = *reinterpret_cast<const float4*>(zrow + t * 16);
        float4 u1 = *reinterpret_cast<const float4*>(zrow + t * 16 + 4);
        f16x8 h;
        h[0] = (_Float16)u0.x; h[1] = (_Float16)u0.y;
        h[2] = (_Float16)u0.z; h[3] = (_Float16)u0.w;
        h[4] = (_Float16)u1.x; h[5] = (_Float16)u1.y;
        h[6] = (_Float16)u1.z; h[7] = (_Float16)u1.w;
        a[t] = h;
    }

    const float INF = __uint_as_float(0x7F800000u);
    float t1[16], t2[16];
#pragma unroll
    for (int s = 0; s < 16; ++s) { t1[s] = INF; t2[s] = INF; }

    const f32x16 zz = {};

    int cur = 0;
#pragma unroll 1
    for (int it = 0; it < 16; ++it) {
        if (it < 15) {
            const _Float16* wb = Wre + (size_t)(it + 1) * 16384;
#pragma unroll
            for (int j = 0; j < 8; ++j)
                gll16(wb + j * 2048 + tid * 8, &Bs[cur ^ 1][j * 2048 + tid * 8]);
            asm volatile("s_waitcnt vmcnt(8)" ::: "memory");  // cur landed, next in flight
        } else {
            asm volatile("s_waitcnt vmcnt(0)" ::: "memory");
        }
        __builtin_amdgcn_s_barrier();

        float w2v[4];
#pragma unroll
        for (int ct = 0; ct < 4; ++ct) w2v[ct] = W2s[it * 128 + ct * 32 + l31];

        const _Float16* bb = &Bs[cur][g2 * 256 + l31 * 8];
        f32x16 acc[4];
        __builtin_amdgcn_s_setprio(1);
#pragma unroll
        for (int ct = 0; ct < 4; ++ct) {
#pragma unroll
            for (int t = 0; t < 8; ++t) {
                f16x8 b = *reinterpret_cast<const f16x8*>(bb + ct * 4096 + t * 512);
                acc[ct] = __builtin_amdgcn_mfma_f32_32x32x16_f16(
                    a[t], b, (t == 0) ? zz : acc[ct], 0, 0, 0);
            }
        }
        __builtin_amdgcn_s_setprio(0);

        // epilogue: d = w2 - acc/64 ; per-row top-2 MIN, col idx in low 11 bits
#pragma unroll
        for (int ct = 0; ct < 4; ++ct) {
            unsigned ci = (unsigned)(it * 128 + ct * 32 + l31);
#pragma unroll
            for (int r = 0; r < 16; ++r) {
                float d = fmaf(-0.015625f, acc[ct][r], w2v[ct]);
                float df = __uint_as_float((__float_as_uint(d) & 0xFFFFF800u) | ci);
                t2[r] = __builtin_amdgcn_fmed3f(df, t1[r], t2[r]);
                t1[r] = fminf(t1[r], df);
            }
        }

        __builtin_amdgcn_s_barrier();
        cur ^= 1;
    }

    // merge across the 32 col-lanes (min semantics); rows differ by g2
#pragma unroll
    for (int s = 0; s < 16; ++s) {
        float v1 = t1[s], v2 = t2[s];
#pragma unroll
        for (int msk = 1; msk < 32; msk <<= 1) {
            float o1 = __shfl_xor(v1, msk, 64);
            float o2 = __shfl_xor(v2, msk, 64);
            float mx = fmaxf(v1, o1);
            v1 = fminf(v1, o1);
            v2 = fminf(fminf(v2, o2), mx);
        }
        if (l31 == 0) {
            int rl = wid * 32 + (s & 3) + 8 * (s >> 2) + 4 * g2;
            T2s[rl] = make_float2(v1, v2);
        }
    }
    __syncthreads();

    // fused resolve: delta-guarded exact fp32 re-score (rare), assign+count
    if (tid < 128) {
        int row = rb * 128 + tid;
        float2 t2v = T2s[tid];
        unsigned u1 = __float_as_uint(t2v.x);
        unsigned u2 = __float_as_uint(t2v.y);
        int c1 = (int)(u1 & 2047u), c2 = (int)(u2 & 2047u);
        float d1 = __uint_as_float(u1 & 0xFFFFF800u);
        float d2 = __uint_as_float(u2 & 0xFFFFF800u);

        int res = c1;
        if (d2 - d1 <= 1e-3f) {
            int cols[2] = {c1, c2};
            const float4* zp = reinterpret_cast<const float4*>(Z + (size_t)row * DD);
            float s0 = 0.f, s1 = 0.f, s2 = 0.f, s3 = 0.f;
            for (int q = 0; q < 32; ++q) {
                float4 z = zp[q];
                s0 = fmaf(z.x, z.x, s0);
                s1 = fmaf(z.y, z.y, s1);
                s2 = fmaf(z.z, z.z, s2);
                s3 = fmaf(z.w, z.w, s3);
            }
            float z2v = (s0 + s1) + (s2 + s3);
            unsigned long long be = ~0ull;
            for (int i = 0; i < 2; ++i) {
                int k = cols[i];
                const float4* wp = reinterpret_cast<const float4*>(Wd + (size_t)k * DD);
                float a0 = 0.f, a1 = 0.f, a2 = 0.f, a3 = 0.f;
                for (int q = 0; q < 32; ++q) {
                    float4 zq = zp[q];
                    float4 wq = wp[q];
                    a0 = fmaf(zq.x, wq.x, a0);
                    a1 = fmaf(zq.y, wq.y, a1);
                    a2 = fmaf(zq.z, wq.z, a2);
                    a3 = fmaf(zq.w, wq.w, a3);
                }
                float sdot = (a0 + a1) + (a2 + a3);
                float tt = __fsub_rn(z2v, __fmul_rn(2.0f, sdot));
                float dist = __fadd_rn(tt, W2s[k]);
                unsigned long long key =
                    (((unsigned long long)encf(dist)) << 32) | (unsigned)k;
                if (key < be) be = key;
            }
            res = (int)(be & 0xffffffffu);
        }
        assign[row] = res;
        atomicAdd(&counts[res], 1.0f);
    }
}

// ---- scan: exclusive prefix over 2048 counts -> start, cursor ----
__global__ __launch_bounds__(256) void vq_scan(const float* __restrict__ counts,
                                               int* __restrict__ start,
                                               int* __restrict__ cursor)
{
    __shared__ int ps[256];
    int tid = threadIdx.x;
    int c[8];
    int tot = 0;
#pragma unroll
    for (int j = 0; j < 8; ++j) { c[j] = (int)counts[tid * 8 + j]; tot += c[j]; }
    ps[tid] = tot;
    __syncthreads();
    for (int off = 1; off < 256; off <<= 1) {
        int v = (tid >= off) ? ps[tid - off] : 0;
        __syncthreads();
        ps[tid] += v;
        __syncthreads();
    }
    int base = ps[tid] - tot;
#pragma unroll
    for (int j = 0; j < 8; ++j) {
        start[tid * 8 + j] = base;
        cursor[tid * 8 + j] = base;
        base += c[j];
    }
}

// ---- permute: row ids grouped by assigned code ----
__global__ __launch_bounds__(256) void vq_permute(const int* __restrict__ assign,
                                                  int* __restrict__ cursor,
                                                  int* __restrict__ order)
{
    int row = blockIdx.x * 256 + threadIdx.x;
    int k = assign[row];
    int pos = atomicAdd(&cursor[k], 1);
    order[pos] = row;
}

// ---- accumulate + update + st_out scatter + exact commit-loss ----
__global__ __launch_bounds__(128) void vq_accum_update(const float* __restrict__ Z,
                                                       const float* __restrict__ Wd,
                                                       const float* __restrict__ dict_cnt,
                                                       const float* __restrict__ counts,
                                                       const int* __restrict__ start,
                                                       const int* __restrict__ order,
                                                       float* __restrict__ w_new_out,
                                                       float* __restrict__ c_new_out,
                                                       float* __restrict__ st_out,
                                                       float* __restrict__ bins)
{
    int k = blockIdx.x;
    int d = threadIdx.x;
    int n = (int)counts[k];
    int st = start[k];

    float sum = 0.f, sq = 0.f;
    int i = 0;
    for (; i + 8 <= n; i += 8) {
        int o0 = order[st + i + 0];
        int o1 = order[st + i + 1];
        int o2 = order[st + i + 2];
        int o3 = order[st + i + 3];
        int o4 = order[st + i + 4];
        int o5 = order[st + i + 5];
        int o6 = order[st + i + 6];
        int o7 = order[st + i + 7];
        float v0 = Z[(size_t)o0 * DD + d];
        float v1 = Z[(size_t)o1 * DD + d];
        float v2 = Z[(size_t)o2 * DD + d];
        float v3 = Z[(size_t)o3 * DD + d];
        float v4 = Z[(size_t)o4 * DD + d];
        float v5 = Z[(size_t)o5 * DD + d];
        float v6 = Z[(size_t)o6 * DD + d];
        float v7 = Z[(size_t)o7 * DD + d];
        sum += ((v0 + v1) + (v2 + v3)) + ((v4 + v5) + (v6 + v7));
        sq = fmaf(v0, v0, sq);
        sq = fmaf(v1, v1, sq);
        sq = fmaf(v2, v2, sq);
        sq = fmaf(v3, v3, sq);
        sq = fmaf(v4, v4, sq);
        sq = fmaf(v5, v5, sq);
        sq = fmaf(v6, v6, sq);
        sq = fmaf(v7, v7, sq);
    }
    for (; i < n; ++i) {
        float v = Z[(size_t)order[st + i] * DD + d];
        sum += v;
        sq = fmaf(v, v, sq);
    }

    float cnt = dict_cnt[k];
    float ck = counts[k];
    bool assigned = n > 0;
    float cn = assigned ? __fadd_rn(__fmul_rn(0.99f, cnt), __fmul_rn(0.01f, ck)) : cnt;
    float w = Wd[(size_t)k * DD + d];
    float wn = w;
    if (assigned) {
        float num = __fmul_rn(0.01f, sum);
        wn = __fadd_rn(__fmul_rn(0.99f, w), num / fmaxf(cn, 1e-12f));
    }
    w_new_out[(size_t)k * DD + d] = wn;
    if (d == 0) c_new_out[k] = cn;

    // straight-through output: every row of this cluster gets w_new[k]
    int j = 0;
    for (; j + 8 <= n; j += 8) {
        int o0 = order[st + j + 0];
        int o1 = order[st + j + 1];
        int o2 = order[st + j + 2];
        int o3 = order[st + j + 3];
        int o4 = order[st + j + 4];
        int o5 = order[st + j + 5];
        int o6 = order[st + j + 6];
        int o7 = order[st + j + 7];
        st_out[(size_t)o0 * DD + d] = wn;
        st_out[(size_t)o1 * DD + d] = wn;
        st_out[(size_t)o2 * DD + d] = wn;
        st_out[(size_t)o3 * DD + d] = wn;
        st_out[(size_t)o4 * DD + d] = wn;
        st_out[(size_t)o5 * DD + d] = wn;
        st_out[(size_t)o6 * DD + d] = wn;
        st_out[(size_t)o7 * DD + d] = wn;
    }
    for (; j < n; ++j)
        st_out[(size_t)order[st + j] * DD + d] = wn;

    // exact commit-loss partial: sum_i (z_i - wn)^2 = sq - 2*wn*sum + n*wn^2
    float p = fmaf(ck, wn * wn, fmaf(-2.0f * wn, sum, sq));
#pragma unroll
    for (int off = 32; off; off >>= 1) p += __shfl_down(p, off, 64);
    __shared__ float sm[2];
    if ((threadIdx.x & 63) == 0) sm[threadIdx.x >> 6] = p;
    __syncthreads();
    if (threadIdx.x == 0) atomicAdd(&bins[(k & 63) * 16], sm[0] + sm[1]);
}

// ---- finish: loss = sum(bins)/N ----
__global__ void vq_finish(const float* __restrict__ bins,
                          float* __restrict__ out_loss)
{
    if (threadIdx.x == 0) {
        float s = 0.f;
        for (int i = 0; i < 64; ++i) s += bins[i * 16];
        out_loss[0] = s * (1.0f / 65536.0f);
    }
}

extern "C" void kernel_launch(void* const* d_in, const int* in_sizes, int n_in,
                              void* d_out, int out_size, void* d_ws, size_t ws_size,
                              hipStream_t stream)
{
    const float* Z        = (const float*)d_in[0];
    const float* Wd       = (const float*)d_in[1];
    const float* dict_cnt = (const float*)d_in[2];

    float* out      = (float*)d_out;
    float* st_out   = out;
    float* out_loss = out + (size_t)NN * DD;
    float* w_new    = out_loss + 1;
    float* c_new    = w_new + (size_t)KK * DD;

    char* ws = (char*)d_ws;
    _Float16* Wre  = (_Float16*)ws;                      //    524,288 B
    float* w2      = (float*)(ws + 524288);              //      8,192 B
    int* assign    = (int*)(ws + 532480);                //    262,144 B
    float* counts  = (float*)(ws + 794624);              //      8,192 B
    float* bins    = (float*)(ws + 802816);              //      4,096 B
    int* start     = (int*)(ws + 806912);                //      8,192 B
    int* cursor    = (int*)(ws + 815104);                //      8,192 B
    int* order     = (int*)(ws + 823296);                //    262,144 B

    // counts + bins contiguous: one memset
    hipMemsetAsync(counts, 0, 8192 + 4096, stream);

    vq_prep<<<KK / 16, 256, 0, stream>>>(Wd, Wre, w2);
    vq_gemm<<<NN / 128, 256, 0, stream>>>(Z, Wre, w2, Wd, assign, counts);
    vq_scan<<<1, 256, 0, stream>>>(counts, start, cursor);
    vq_permute<<<NN / 256, 256, 0, stream>>>(assign, cursor, order);
    vq_accum_update<<<KK, 128, 0, stream>>>(Z, Wd, dict_cnt, counts, start, order,
                                            w_new, c_new, st_out, bins);
    vq_finish<<<1, 64, 0, stream>>>(bins, out_loss);
}